// Round 2
// baseline (439.189 us; speedup 1.0000x reference)
//
#include <hip/hip_runtime.h>
#include <hip/hip_bf16.h>
#include <math.h>

#define NNODES 4096
#define NCOLS  96          // B*T
#define NROWS  12288       // K*NNODES
#define KSEG   4           // K-split ways (each wave does 1024 k)
#define KLEN   (NNODES / KSEG)

typedef __attribute__((ext_vector_type(8))) short short8;
typedef __attribute__((ext_vector_type(4))) float float4v;

// ---------------------------------------------------------------------------
// Dtype probe: flag[0]=1 => inputs fp32, 0 => bf16. (Validated: fp32 on this
// harness — earlier rounds passed through the fp32 path.)
// ---------------------------------------------------------------------------
__global__ void probe_dtype(const unsigned int* __restrict__ aw, int* __restrict__ flag) {
    int tid = threadIdx.x;
    unsigned w = aw[tid];
    unsigned e = (w >> 7) & 0xffu;
    bool insane = (e >= 0xC0u) || (e <= 0x30u);
    unsigned long long m = __ballot(insane);
    if (tid == 0) flag[0] = (__popcll(m) >= 16) ? 1 : 0;
}

__device__ __forceinline__ float ldf(const void* p, size_t i, int isf32) {
    return isf32 ? ((const float*)p)[i]
                 : __bfloat162float(((const __hip_bfloat16*)p)[i]);
}

__device__ __forceinline__ void ld8(float* d, const void* p, size_t e, int isf32) {
    if (isf32) {
        const float4* s = (const float4*)((const float*)p + e);
        float4 f0 = s[0], f1 = s[1];
        d[0] = f0.x; d[1] = f0.y; d[2] = f0.z; d[3] = f0.w;
        d[4] = f1.x; d[5] = f1.y; d[6] = f1.z; d[7] = f1.w;
    } else {
        const __hip_bfloat16* s = (const __hip_bfloat16*)p + e;
#pragma unroll
        for (int j = 0; j < 8; j++) d[j] = __bfloat162float(s[j]);
    }
}

// pack 8 fp32 -> short8 of bf16 (RNE via __float2bfloat16)
__device__ __forceinline__ short8 cvt8(float4 a, float4 b) {
    union { short8 v; __hip_bfloat16 h[8]; } u;
    u.h[0] = __float2bfloat16(a.x); u.h[1] = __float2bfloat16(a.y);
    u.h[2] = __float2bfloat16(a.z); u.h[3] = __float2bfloat16(a.w);
    u.h[4] = __float2bfloat16(b.x); u.h[5] = __float2bfloat16(b.y);
    u.h[6] = __float2bfloat16(b.z); u.h[7] = __float2bfloat16(b.w);
    return u.v;
}

// ---------------------------------------------------------------------------
// Kernel 1 (v2): y = adj(12288x4096) @ X^T, bf16 MFMA 16x16x32, NO LDS.
// Each lane's fragment is 8 consecutive floats of one row, so fragments are
// loaded per-lane straight from global (wave touches 16 rows x 128B contig).
// One wave owns a 16-row x 96-col output tile over a 1024-k segment (KSEG=4
// K-split -> 3072 waves = 3/SIMD; partials to 4 ws slices, summed in epilogue).
// Zero barriers; 2-set register prefetch pipeline (all indices compile-time,
// rule #20). C/D mapping P0 (HW-validated): col=lane&15, row=(lane>>4)*4+reg.
// ---------------------------------------------------------------------------
__global__ __launch_bounds__(256) void gemm_y(
    const void* __restrict__ adjv, const void* __restrict__ xv,
    float* __restrict__ yws, const int* __restrict__ flag)
{
    const int tid = threadIdx.x;
    const int isf32 = flag[0];
    const int wv = tid >> 6;
    const int ln = tid & 63;
    const int fr = ln & 15;
    const int fq = ln >> 4;

    const int gw = blockIdx.x * 4 + wv;    // 0..3071
    const int rt = gw >> 2;                // row tile 0..767 (16 rows each)
    const int ks = gw & 3;                 // k segment 0..3
    const int k0 = ks * KLEN;

    float4v acc[6];
#pragma unroll
    for (int i = 0; i < 6; i++) acc[i] = (float4v){0.f, 0.f, 0.f, 0.f};

    if (isf32) {
        const float* adjf = (const float*)adjv;
        const float* xf   = (const float*)xv;
        const float* aptr = adjf + (size_t)(rt * 16 + fr) * NNODES + k0 + fq * 8;
        const float* xptr[6];
#pragma unroll
        for (int ct = 0; ct < 6; ct++)
            xptr[ct] = xf + (size_t)(ct * 16 + fr) * NNODES + k0 + fq * 8;

        float4 raA[2], rxA[6][2], raB[2], rxB[6][2];

#define LOADF(RA, RX, KB) {                                                   \
        { const float* p = aptr + (KB);                                       \
          RA[0] = *(const float4*)p; RA[1] = *(const float4*)(p + 4); }       \
        _Pragma("unroll")                                                     \
        for (int ct = 0; ct < 6; ct++) {                                      \
            const float* p = xptr[ct] + (KB);                                 \
            RX[ct][0] = *(const float4*)p; RX[ct][1] = *(const float4*)(p + 4);\
        } }
#define COMPF(RA, RX) {                                                       \
        short8 a = cvt8(RA[0], RA[1]);                                        \
        _Pragma("unroll")                                                     \
        for (int ct = 0; ct < 6; ct++) {                                      \
            short8 b = cvt8(RX[ct][0], RX[ct][1]);                            \
            acc[ct] = __builtin_amdgcn_mfma_f32_16x16x32_bf16(a, b, acc[ct], 0, 0, 0); \
        } }

        LOADF(raA, rxA, 0);
        for (int it = 0; it < KLEN / 32; it += 2) {
            LOADF(raB, rxB, (it + 1) * 32);
            COMPF(raA, rxA);
            if (it + 2 < KLEN / 32) LOADF(raA, rxA, (it + 2) * 32);
            COMPF(raB, rxB);
        }
#undef LOADF
#undef COMPF
    } else {
        // bf16 input path (insurance): one 16B load per fragment
        const __hip_bfloat16* adjb = (const __hip_bfloat16*)adjv;
        const __hip_bfloat16* xb   = (const __hip_bfloat16*)xv;
        const __hip_bfloat16* aptr = adjb + (size_t)(rt * 16 + fr) * NNODES + k0 + fq * 8;
        const __hip_bfloat16* xptr[6];
#pragma unroll
        for (int ct = 0; ct < 6; ct++)
            xptr[ct] = xb + (size_t)(ct * 16 + fr) * NNODES + k0 + fq * 8;

        uint4 raA, rxA[6], raB, rxB[6];

#define LOADB(RA, RX, KB) {                                                   \
        RA = *(const uint4*)(aptr + (KB));                                    \
        _Pragma("unroll")                                                     \
        for (int ct = 0; ct < 6; ct++) RX[ct] = *(const uint4*)(xptr[ct] + (KB)); }
#define COMPB(RA, RX) {                                                       \
        short8 a = *(const short8*)&RA;                                       \
        _Pragma("unroll")                                                     \
        for (int ct = 0; ct < 6; ct++) {                                      \
            short8 b = *(const short8*)&RX[ct];                               \
            acc[ct] = __builtin_amdgcn_mfma_f32_16x16x32_bf16(a, b, acc[ct], 0, 0, 0); \
        } }

        LOADB(raA, rxA, 0);
        for (int it = 0; it < KLEN / 32; it += 2) {
            LOADB(raB, rxB, (it + 1) * 32);
            COMPB(raA, rxA);
            if (it + 2 < KLEN / 32) LOADB(raA, rxA, (it + 2) * 32);
            COMPB(raB, rxB);
        }
#undef LOADB
#undef COMPB
    }

    // store partials: slice ks, P0 mapping
    float* yo = yws + (size_t)ks * NROWS * NCOLS;
#pragma unroll
    for (int ct = 0; ct < 6; ct++)
#pragma unroll
        for (int rg = 0; rg < 4; rg++) {
            size_t r = (size_t)rt * 16 + fq * 4 + rg;
            yo[r * NCOLS + ct * 16 + fr] = acc[ct][rg];
        }
}

// ---------------------------------------------------------------------------
// Kernel 2: epilogue. 4 lanes (a quad) per (b,n): each lane owns 3 t's of the
// cheb/sgc sum, quad-reduced via shfl_xor; GLU o-range split across the quad.
// Sums the 4 K-split partial slices of yws.
// 512 blocks x 256 thr = 2048 waves = 2 waves/SIMD.
// yws slice layout [k*4096+n][b*12+t].
// ---------------------------------------------------------------------------
__global__ __launch_bounds__(256) void epilogue_kernel(
    const void* __restrict__ xv, const float* __restrict__ yws,
    const void* __restrict__ chebv, const void* __restrict__ gcnwv,
    const void* __restrict__ gcnbv, const void* __restrict__ g1wv,
    const void* __restrict__ g1bv, const void* __restrict__ g2wv,
    const void* __restrict__ g2bv,
    float* __restrict__ out, const int* __restrict__ flag)
{
    __shared__ float gwL[9216];   // [t][j*12+o]
    __shared__ float cwL[192];    // [j*3+k]
    __shared__ float w1L[216];    // [o*18 + c*3 + kh]  (kw=1 tap)
    __shared__ float w2L[216];
    __shared__ float wbL[36];

    const int tid = threadIdx.x;
    const int isf32 = flag[0];

    for (int i = tid; i < 9216; i += 256) {
        int o = i / 768, t = (i / 64) % 12, j = i % 64;   // gcn_w flat (o,t,0,j)
        gwL[t * 768 + j * 12 + o] = ldf(gcnwv, i, isf32);
    }
    if (tid < 192) cwL[tid] = ldf(chebv, tid, isf32);
    if (tid < 216) {
        w1L[tid] = ldf(g1wv, (size_t)tid * 3 + 1, isf32);
        w2L[tid] = ldf(g2wv, (size_t)tid * 3 + 1, isf32);
    }
    if (tid < 12) {
        wbL[tid]      = ldf(gcnbv, tid, isf32);
        wbL[12 + tid] = ldf(g1bv, tid, isf32);
        wbL[24 + tid] = ldf(g2bv, tid, isf32);
    }
    __syncthreads();

    const int gid = blockIdx.x * 256 + tid;   // 0..131071
    const int pr  = gid >> 2;                 // (b,n) pair 0..32767
    const int tq  = gid & 3;                  // t-quarter 0..3
    const int b = pr >> 12;
    const int n = pr & (NNODES - 1);

    // y values for this lane's 3 t's: sum the KSEG partial slices
    float yk[3][3];
#pragma unroll
    for (int k = 0; k < 3; k++) { yk[k][0] = 0.f; yk[k][1] = 0.f; yk[k][2] = 0.f; }
#pragma unroll
    for (int s = 0; s < KSEG; s++) {
        const float* base = yws + (size_t)s * NROWS * NCOLS;
#pragma unroll
        for (int k = 0; k < 3; k++) {
            const float* yp = base + ((size_t)(k * NNODES + n)) * NCOLS + b * 12 + tq * 3;
            yk[k][0] += yp[0]; yk[k][1] += yp[1]; yk[k][2] += yp[2];
        }
    }

    // ---- cheb -> relu -> partial sgc over 3 t's ----
    float sg[12];
#pragma unroll
    for (int o = 0; o < 12; o++) sg[o] = 0.f;
#pragma unroll
    for (int i = 0; i < 3; i++) {
        const float y0 = yk[0][i], y1 = yk[1][i], y2 = yk[2][i];
        const float* gwt = gwL + (tq * 3 + i) * 768;
#pragma unroll 4
        for (int j = 0; j < 64; j++) {
            float h = y0 * cwL[j * 3] + y1 * cwL[j * 3 + 1] + y2 * cwL[j * 3 + 2];
            h = fmaxf(h, 0.f);
#pragma unroll
            for (int o = 0; o < 12; o++) sg[o] += h * gwt[j * 12 + o];
        }
    }
    // quad reduction: all 4 lanes end with the full t-sum
#pragma unroll
    for (int o = 0; o < 12; o++) {
        sg[o] += __shfl_xor(sg[o], 1);
        sg[o] += __shfl_xor(sg[o], 2);
    }

    // ---- GLU (dilated conv taps n-2, n, n+2; only kw=1 alive); this lane
    // handles o = tq*3 .. tq*3+2 ----
    float xa[18], xg[18];
#pragma unroll
    for (int c = 0; c < 6; c++)
#pragma unroll
        for (int kh = 0; kh < 3; kh++) {
            int m = n + 2 * kh - 2;
            bool ok = ((unsigned)m < (unsigned)NNODES);
            xa[c * 3 + kh] = ok ? ldf(xv, ((size_t)(b * 12 + c)) * NNODES + m, isf32) : 0.f;
            xg[c * 3 + kh] = ok ? ldf(xv, ((size_t)(b * 12 + c + 6)) * NNODES + m, isf32) : 0.f;
        }

#pragma unroll
    for (int i = 0; i < 3; i++) {
        const int o = tq * 3 + i;
        float av = wbL[12 + o], gv = wbL[24 + o];
#pragma unroll
        for (int q = 0; q < 18; q++) {
            av += xa[q] * w1L[o * 18 + q];
            gv += xg[q] * w2L[o * 18 + q];
        }
        float s = 1.f / (1.f + expf(-gv));
        out[((size_t)(b * 12 + o)) * NNODES + n] = av * s + sg[o] + wbL[o];
    }
}

// ---------------------------------------------------------------------------
// Fallback single kernel (only if ws too small): round-5 verified path.
// ---------------------------------------------------------------------------
__global__ __launch_bounds__(64) void fused_simple(
    const void* __restrict__ xv, const void* __restrict__ adjv,
    const void* __restrict__ chebv, const void* __restrict__ gcnwv,
    const void* __restrict__ gcnbv, const void* __restrict__ g1wv,
    const void* __restrict__ g1bv, const void* __restrict__ g2wv,
    const void* __restrict__ g2bv,
    float* __restrict__ out, const int* __restrict__ flag)
{
    __shared__ float gwL[9216];
    __shared__ float cwL[192];
    __shared__ float w1L[216];
    __shared__ float w2L[216];
    __shared__ float wbL[36];

    const int tid = threadIdx.x;
    const int isf32 = flag[0];

    for (int i = tid; i < 9216; i += 64) {
        int o = i / 768, t = (i / 64) % 12, j = i % 64;
        gwL[t * 768 + j * 12 + o] = ldf(gcnwv, i, isf32);
    }
    for (int i = tid; i < 192; i += 64) cwL[i] = ldf(chebv, i, isf32);
    for (int i = tid; i < 216; i += 64) {
        w1L[i] = ldf(g1wv, (size_t)i * 3 + 1, isf32);
        w2L[i] = ldf(g2wv, (size_t)i * 3 + 1, isf32);
    }
    if (tid < 12) {
        wbL[tid]      = ldf(gcnbv, tid, isf32);
        wbL[12 + tid] = ldf(g1bv, tid, isf32);
        wbL[24 + tid] = ldf(g2bv, tid, isf32);
    }
    __syncthreads();

    const int g = blockIdx.x * 64 + tid;
    const int b = g >> 12;
    const int n = g & (NNODES - 1);

    float y[3][12];
#pragma unroll
    for (int k = 0; k < 3; k++)
#pragma unroll
        for (int t = 0; t < 12; t++) y[k][t] = 0.f;

    for (int m0 = 0; m0 < NNODES; m0 += 8) {
        float a0[8], a1[8], a2[8];
        ld8(a0, adjv, ((size_t)(0 * NNODES + n)) * NNODES + m0, isf32);
        ld8(a1, adjv, ((size_t)(1 * NNODES + n)) * NNODES + m0, isf32);
        ld8(a2, adjv, ((size_t)(2 * NNODES + n)) * NNODES + m0, isf32);
#pragma unroll
        for (int t = 0; t < 12; t++) {
            float x8[8];
            ld8(x8, xv, ((size_t)(b * 12 + t)) * NNODES + m0, isf32);
#pragma unroll
            for (int j = 0; j < 8; j++) {
                y[0][t] += a0[j] * x8[j];
                y[1][t] += a1[j] * x8[j];
                y[2][t] += a2[j] * x8[j];
            }
        }
    }

    float sg[12];
#pragma unroll
    for (int o = 0; o < 12; o++) sg[o] = wbL[o];
    for (int t = 0; t < 12; t++) {
        const float y0 = y[0][t], y1 = y[1][t], y2 = y[2][t];
        const float* gwt = gwL + t * 768;
#pragma unroll 4
        for (int j = 0; j < 64; j++) {
            float h = y0 * cwL[j * 3] + y1 * cwL[j * 3 + 1] + y2 * cwL[j * 3 + 2];
            h = fmaxf(h, 0.f);
#pragma unroll
            for (int o = 0; o < 12; o++) sg[o] += h * gwt[j * 12 + o];
        }
    }

    float xa[18], xg[18];
#pragma unroll
    for (int c = 0; c < 6; c++)
#pragma unroll
        for (int kh = 0; kh < 3; kh++) {
            int m = n + 2 * kh - 2;
            bool ok = ((unsigned)m < (unsigned)NNODES);
            xa[c * 3 + kh] = ok ? ldf(xv, ((size_t)(b * 12 + c)) * NNODES + m, isf32) : 0.f;
            xg[c * 3 + kh] = ok ? ldf(xv, ((size_t)(b * 12 + c + 6)) * NNODES + m, isf32) : 0.f;
        }

#pragma unroll
    for (int o = 0; o < 12; o++) {
        float av = wbL[12 + o], gv = wbL[24 + o];
#pragma unroll
        for (int i = 0; i < 18; i++) {
            av += xa[i] * w1L[o * 18 + i];
            gv += xg[i] * w2L[o * 18 + i];
        }
        float s = 1.f / (1.f + expf(-gv));
        out[((size_t)(b * 12 + o)) * NNODES + n] = av * s + sg[o];
    }
}

// ---------------------------------------------------------------------------
extern "C" void kernel_launch(void* const* d_in, const int* in_sizes, int n_in,
                              void* d_out, int out_size, void* d_ws, size_t ws_size,
                              hipStream_t stream)
{
    int* flag = (int*)d_ws;                       // 64 B reserved
    float* yws = (float*)((char*)d_ws + 64);      // KSEG slices of 12288*96 fp32
    const size_t need = 64 + (size_t)KSEG * NROWS * NCOLS * 4;

    hipLaunchKernelGGL(probe_dtype, dim3(1), dim3(64), 0, stream,
                       (const unsigned int*)d_in[1], flag);

    if (ws_size >= need) {
        hipLaunchKernelGGL(gemm_y, dim3(768), dim3(256), 0, stream,
                           d_in[1], d_in[0], yws, flag);
        hipLaunchKernelGGL(epilogue_kernel, dim3(512), dim3(256), 0, stream,
                           d_in[0], yws, d_in[2], d_in[3], d_in[4],
                           d_in[5], d_in[6], d_in[7], d_in[8],
                           (float*)d_out, flag);
    } else {
        hipLaunchKernelGGL(fused_simple, dim3(512), dim3(64), 0, stream,
                           d_in[0], d_in[1], d_in[2], d_in[3], d_in[4],
                           d_in[5], d_in[6], d_in[7], d_in[8],
                           (float*)d_out, flag);
    }
}

// Round 3
// 422.256 us; speedup vs baseline: 1.0401x; 1.0401x over previous
//
#include <hip/hip_runtime.h>
#include <hip/hip_bf16.h>
#include <math.h>

#define NNODES 4096
#define NCOLS  96          // B*T
#define NROWS  12288       // K*NNODES
#define KSEG   4           // K-split ways
#define KLEN   (NNODES / KSEG)   // 1024
#define BKS    64                // k per LDS stage
#define NSTEP  (KLEN / BKS)      // 16
#define BMR    48                // rows per block

typedef __attribute__((ext_vector_type(8))) short short8;
typedef __attribute__((ext_vector_type(4))) float float4v;

// ---------------------------------------------------------------------------
// Dtype probe: flag[0]=1 => inputs fp32, 0 => bf16. (Validated: fp32 on this
// harness.)
// ---------------------------------------------------------------------------
__global__ void probe_dtype(const unsigned int* __restrict__ aw, int* __restrict__ flag) {
    int tid = threadIdx.x;
    unsigned w = aw[tid];
    unsigned e = (w >> 7) & 0xffu;
    bool insane = (e >= 0xC0u) || (e <= 0x30u);
    unsigned long long m = __ballot(insane);
    if (tid == 0) flag[0] = (__popcll(m) >= 16) ? 1 : 0;
}

__device__ __forceinline__ float ldf(const void* p, size_t i, int isf32) {
    return isf32 ? ((const float*)p)[i]
                 : __bfloat162float(((const __hip_bfloat16*)p)[i]);
}

__device__ __forceinline__ void ld8(float* d, const void* p, size_t e, int isf32) {
    if (isf32) {
        const float4* s = (const float4*)((const float*)p + e);
        float4 f0 = s[0], f1 = s[1];
        d[0] = f0.x; d[1] = f0.y; d[2] = f0.z; d[3] = f0.w;
        d[4] = f1.x; d[5] = f1.y; d[6] = f1.z; d[7] = f1.w;
    } else {
        const __hip_bfloat16* s = (const __hip_bfloat16*)p + e;
#pragma unroll
        for (int j = 0; j < 8; j++) d[j] = __bfloat162float(s[j]);
    }
}

// pack 8 fp32 -> short8 of bf16 (RNE via __float2bfloat16)
__device__ __forceinline__ short8 cvt8(float4 a, float4 b) {
    union { short8 v; __hip_bfloat16 h[8]; } u;
    u.h[0] = __float2bfloat16(a.x); u.h[1] = __float2bfloat16(a.y);
    u.h[2] = __float2bfloat16(a.z); u.h[3] = __float2bfloat16(a.w);
    u.h[4] = __float2bfloat16(b.x); u.h[5] = __float2bfloat16(b.y);
    u.h[6] = __float2bfloat16(b.z); u.h[7] = __float2bfloat16(b.w);
    return u.v;
}

// ---------------------------------------------------------------------------
// Kernel 0b: convert X (96 x 4096) to bf16 in workspace (once; L2-resident
// thereafter). 192 blocks x 256 thr x 8 elems.
// ---------------------------------------------------------------------------
__global__ __launch_bounds__(256) void cvt_x(
    const void* __restrict__ xv, __hip_bfloat16* __restrict__ xbf,
    const int* __restrict__ flag)
{
    const int isf32 = flag[0];
    const int i = (blockIdx.x * 256 + threadIdx.x) * 8;
    if (isf32) {
        const float* xf = (const float*)xv;
        float4 f0 = *(const float4*)(xf + i);
        float4 f1 = *(const float4*)(xf + i + 4);
        short8 v = cvt8(f0, f1);
        *(short8*)(xbf + i) = v;
    } else {
        *(uint4*)(xbf + i) = *(const uint4*)((const __hip_bfloat16*)xv + i);
    }
}

// ---------------------------------------------------------------------------
// Kernel 1 (v3): y = adj @ X^T, bf16 MFMA 16x16x32.
//  - adj: direct per-lane global->reg, 2-iteration-deep prefetch (2 static
//    reg sets, even/odd unroll). Rows are wave-exclusive so LDS buys nothing.
//  - X: bf16 (pre-converted), staged reg->LDS triple-buffered, XOR-swizzled
//    chunks (slot = c ^ (r&7)) -> uniform bank load on ds_read_b128.
//  - raw s_barrier + manual lgkmcnt(0) (NOT __syncthreads: that drains
//    vmcnt(0) and would kill the in-flight adj prefetch).
//  - 1024 blocks (256 row-groups x KSEG=4) x 192 thr, 36 KB LDS ->
//    4 blocks/CU; independent blocks overlap barrier stalls.
// Output: yws slice ks, yws[r*96+col], r=global row, col=b*12+t.
// C/D mapping P0 (HW-validated): col=lane&15, row=(lane>>4)*4+reg.
// ---------------------------------------------------------------------------
__global__ __launch_bounds__(192, 3) void gemm_y(
    const void* __restrict__ adjv, const __hip_bfloat16* __restrict__ xbf,
    float* __restrict__ yws, const int* __restrict__ flag)
{
    __shared__ uint4 Xs[3][96 * 8];     // 36 KB, triple-buffered

    const int tid = threadIdx.x;
    const int isf32 = flag[0];
    const int wv = tid >> 6, ln = tid & 63, fr = ln & 15, fq = ln >> 4;

    const int bid = blockIdx.x;
    const int rt0 = (bid >> 2) * BMR;     // 0..12240
    const int ks  = bid & 3;
    const int k0  = ks * KLEN;

    float4v acc[6];
#pragma unroll
    for (int i = 0; i < 6; i++) acc[i] = (float4v){0.f, 0.f, 0.f, 0.f};

    // X staging: 768 chunks of 16B per buffer; thread covers L = s*192+tid
    int xslot_[4];
    const __hip_bfloat16* xsrc[4];
#pragma unroll
    for (int s = 0; s < 4; s++) {
        int L = s * 192 + tid;
        int r = L >> 3, c = L & 7;
        xslot_[s] = r * 8 + (c ^ (r & 7));
        xsrc[s] = xbf + (size_t)r * NNODES + k0 + c * 8;
    }

    const int arow = rt0 + wv * 16 + fr;  // this lane's adj row

#define XLOAD(R, STEP) { _Pragma("unroll")                                     \
    for (int s = 0; s < 4; s++) R[s] = *(const uint4*)(xsrc[s] + (size_t)(STEP) * BKS); }
#define XWRITE(R, BUF) { _Pragma("unroll")                                     \
    for (int s = 0; s < 4; s++) Xs[BUF][xslot_[s]] = R[s]; }
#define BARRIER() { asm volatile("s_waitcnt lgkmcnt(0)" ::: "memory");         \
    __builtin_amdgcn_s_barrier();                                              \
    __builtin_amdgcn_sched_barrier(0); }

    if (isf32) {
        const float* ap = (const float*)adjv + (size_t)arow * NNODES + k0 + fq * 8;
        uint4 XA[4], XB[4];
        float4 AA[2][2], AB[2][2];

#define ALOADF(R, STEP) { _Pragma("unroll")                                    \
        for (int kq = 0; kq < 2; kq++) {                                       \
            const float* p = ap + (STEP) * BKS + kq * 32;                      \
            R[kq][0] = *(const float4*)p; R[kq][1] = *(const float4*)(p + 4); } }
#define COMPF(R, BUF) { _Pragma("unroll")                                      \
        for (int kq = 0; kq < 2; kq++) {                                       \
            short8 a = cvt8(R[kq][0], R[kq][1]);                               \
            _Pragma("unroll")                                                  \
            for (int ct = 0; ct < 6; ct++) {                                   \
                short8 b = *(const short8*)&Xs[BUF][(ct * 16 + fr) * 8 +       \
                                                    ((kq * 4 + fq) ^ (fr & 7))]; \
                acc[ct] = __builtin_amdgcn_mfma_f32_16x16x32_bf16(a, b, acc[ct], 0, 0, 0); \
            } } }

        XLOAD(XA, 0); ALOADF(AA, 0);
        XLOAD(XB, 1); ALOADF(AB, 1);
        XWRITE(XA, 0);
        BARRIER();

        int b0 = 0;
        for (int t = 0; t < NSTEP; t += 2) {
            // even step t: compute set A from buf b0
            if (t + 1 < NSTEP) XWRITE(XB, (b0 + 1) % 3);
            if (t + 2 < NSTEP) XLOAD(XA, t + 2);          // XA free (X(t) already in LDS)
            COMPF(AA, b0);
            if (t + 2 < NSTEP) ALOADF(AA, t + 2);         // after AA consumed
            BARRIER();
            // odd step t+1: compute set B from buf (b0+1)%3
            if (t + 2 < NSTEP) XWRITE(XA, (b0 + 2) % 3);
            if (t + 3 < NSTEP) XLOAD(XB, t + 3);
            COMPF(AB, (b0 + 1) % 3);
            if (t + 3 < NSTEP) ALOADF(AB, t + 3);
            BARRIER();
            b0 = (b0 + 2) % 3;
        }
#undef ALOADF
#undef COMPF
    } else {
        // bf16 adj path (insurance): one uint4 per kq-fragment
        const __hip_bfloat16* ap = (const __hip_bfloat16*)adjv + (size_t)arow * NNODES + k0 + fq * 8;
        uint4 XA[4], XB[4];
        uint4 AA[2], AB[2];

#define ALOADB(R, STEP) { _Pragma("unroll")                                    \
        for (int kq = 0; kq < 2; kq++)                                         \
            R[kq] = *(const uint4*)(ap + (STEP) * BKS + kq * 32); }
#define COMPB(R, BUF) { _Pragma("unroll")                                      \
        for (int kq = 0; kq < 2; kq++) {                                       \
            short8 a = *(const short8*)&R[kq];                                 \
            _Pragma("unroll")                                                  \
            for (int ct = 0; ct < 6; ct++) {                                   \
                short8 b = *(const short8*)&Xs[BUF][(ct * 16 + fr) * 8 +       \
                                                    ((kq * 4 + fq) ^ (fr & 7))]; \
                acc[ct] = __builtin_amdgcn_mfma_f32_16x16x32_bf16(a, b, acc[ct], 0, 0, 0); \
            } } }

        XLOAD(XA, 0); ALOADB(AA, 0);
        XLOAD(XB, 1); ALOADB(AB, 1);
        XWRITE(XA, 0);
        BARRIER();

        int b0 = 0;
        for (int t = 0; t < NSTEP; t += 2) {
            if (t + 1 < NSTEP) XWRITE(XB, (b0 + 1) % 3);
            if (t + 2 < NSTEP) XLOAD(XA, t + 2);
            COMPB(AA, b0);
            if (t + 2 < NSTEP) ALOADB(AA, t + 2);
            BARRIER();
            if (t + 2 < NSTEP) XWRITE(XA, (b0 + 2) % 3);
            if (t + 3 < NSTEP) XLOAD(XB, t + 3);
            COMPB(AB, (b0 + 1) % 3);
            if (t + 3 < NSTEP) ALOADB(AB, t + 3);
            BARRIER();
            b0 = (b0 + 2) % 3;
        }
#undef ALOADB
#undef COMPB
    }
#undef XLOAD
#undef XWRITE
#undef BARRIER

    // store partials: slice ks, P0 mapping
    float* yo = yws + (size_t)ks * NROWS * NCOLS;
#pragma unroll
    for (int ct = 0; ct < 6; ct++)
#pragma unroll
        for (int rg = 0; rg < 4; rg++) {
            size_t r = (size_t)rt0 + wv * 16 + fq * 4 + rg;
            yo[r * NCOLS + ct * 16 + fr] = acc[ct][rg];
        }
}

// ---------------------------------------------------------------------------
// Kernel 2: epilogue. 4 lanes (a quad) per (b,n): each lane owns 3 t's of the
// cheb/sgc sum, quad-reduced via shfl_xor; GLU o-range split across the quad.
// Sums the KSEG partial slices of yws. 512 blocks x 256 thr.
// yws slice layout [k*4096+n][b*12+t].
// ---------------------------------------------------------------------------
__global__ __launch_bounds__(256) void epilogue_kernel(
    const void* __restrict__ xv, const float* __restrict__ yws,
    const void* __restrict__ chebv, const void* __restrict__ gcnwv,
    const void* __restrict__ gcnbv, const void* __restrict__ g1wv,
    const void* __restrict__ g1bv, const void* __restrict__ g2wv,
    const void* __restrict__ g2bv,
    float* __restrict__ out, const int* __restrict__ flag)
{
    __shared__ float gwL[9216];   // [t][j*12+o]
    __shared__ float cwL[192];    // [j*3+k]
    __shared__ float w1L[216];    // [o*18 + c*3 + kh]  (kw=1 tap)
    __shared__ float w2L[216];
    __shared__ float wbL[36];

    const int tid = threadIdx.x;
    const int isf32 = flag[0];

    for (int i = tid; i < 9216; i += 256) {
        int o = i / 768, t = (i / 64) % 12, j = i % 64;   // gcn_w flat (o,t,0,j)
        gwL[t * 768 + j * 12 + o] = ldf(gcnwv, i, isf32);
    }
    if (tid < 192) cwL[tid] = ldf(chebv, tid, isf32);
    if (tid < 216) {
        w1L[tid] = ldf(g1wv, (size_t)tid * 3 + 1, isf32);
        w2L[tid] = ldf(g2wv, (size_t)tid * 3 + 1, isf32);
    }
    if (tid < 12) {
        wbL[tid]      = ldf(gcnbv, tid, isf32);
        wbL[12 + tid] = ldf(g1bv, tid, isf32);
        wbL[24 + tid] = ldf(g2bv, tid, isf32);
    }
    __syncthreads();

    const int gid = blockIdx.x * 256 + tid;   // 0..131071
    const int pr  = gid >> 2;                 // (b,n) pair 0..32767
    const int tq  = gid & 3;                  // t-quarter 0..3
    const int b = pr >> 12;
    const int n = pr & (NNODES - 1);

    // y values for this lane's 3 t's: sum the KSEG partial slices
    float yk[3][3];
#pragma unroll
    for (int k = 0; k < 3; k++) { yk[k][0] = 0.f; yk[k][1] = 0.f; yk[k][2] = 0.f; }
#pragma unroll
    for (int s = 0; s < KSEG; s++) {
        const float* base = yws + (size_t)s * NROWS * NCOLS;
#pragma unroll
        for (int k = 0; k < 3; k++) {
            const float* yp = base + ((size_t)(k * NNODES + n)) * NCOLS + b * 12 + tq * 3;
            yk[k][0] += yp[0]; yk[k][1] += yp[1]; yk[k][2] += yp[2];
        }
    }

    // ---- cheb -> relu -> partial sgc over 3 t's ----
    float sg[12];
#pragma unroll
    for (int o = 0; o < 12; o++) sg[o] = 0.f;
#pragma unroll
    for (int i = 0; i < 3; i++) {
        const float y0 = yk[0][i], y1 = yk[1][i], y2 = yk[2][i];
        const float* gwt = gwL + (tq * 3 + i) * 768;
#pragma unroll 4
        for (int j = 0; j < 64; j++) {
            float h = y0 * cwL[j * 3] + y1 * cwL[j * 3 + 1] + y2 * cwL[j * 3 + 2];
            h = fmaxf(h, 0.f);
#pragma unroll
            for (int o = 0; o < 12; o++) sg[o] += h * gwt[j * 12 + o];
        }
    }
    // quad reduction: all 4 lanes end with the full t-sum
#pragma unroll
    for (int o = 0; o < 12; o++) {
        sg[o] += __shfl_xor(sg[o], 1);
        sg[o] += __shfl_xor(sg[o], 2);
    }

    // ---- GLU (dilated conv taps n-2, n, n+2; only kw=1 alive); this lane
    // handles o = tq*3 .. tq*3+2 ----
    float xa[18], xg[18];
#pragma unroll
    for (int c = 0; c < 6; c++)
#pragma unroll
        for (int kh = 0; kh < 3; kh++) {
            int m = n + 2 * kh - 2;
            bool ok = ((unsigned)m < (unsigned)NNODES);
            xa[c * 3 + kh] = ok ? ldf(xv, ((size_t)(b * 12 + c)) * NNODES + m, isf32) : 0.f;
            xg[c * 3 + kh] = ok ? ldf(xv, ((size_t)(b * 12 + c + 6)) * NNODES + m, isf32) : 0.f;
        }

#pragma unroll
    for (int i = 0; i < 3; i++) {
        const int o = tq * 3 + i;
        float av = wbL[12 + o], gv = wbL[24 + o];
#pragma unroll
        for (int q = 0; q < 18; q++) {
            av += xa[q] * w1L[o * 18 + q];
            gv += xg[q] * w2L[o * 18 + q];
        }
        float s = 1.f / (1.f + expf(-gv));
        out[((size_t)(b * 12 + o)) * NNODES + n] = av * s + sg[o] + wbL[o];
    }
}

// ---------------------------------------------------------------------------
// Fallback single kernel (only if ws too small): round-5 verified path.
// ---------------------------------------------------------------------------
__global__ __launch_bounds__(64) void fused_simple(
    const void* __restrict__ xv, const void* __restrict__ adjv,
    const void* __restrict__ chebv, const void* __restrict__ gcnwv,
    const void* __restrict__ gcnbv, const void* __restrict__ g1wv,
    const void* __restrict__ g1bv, const void* __restrict__ g2wv,
    const void* __restrict__ g2bv,
    float* __restrict__ out, const int* __restrict__ flag)
{
    __shared__ float gwL[9216];
    __shared__ float cwL[192];
    __shared__ float w1L[216];
    __shared__ float w2L[216];
    __shared__ float wbL[36];

    const int tid = threadIdx.x;
    const int isf32 = flag[0];

    for (int i = tid; i < 9216; i += 64) {
        int o = i / 768, t = (i / 64) % 12, j = i % 64;
        gwL[t * 768 + j * 12 + o] = ldf(gcnwv, i, isf32);
    }
    for (int i = tid; i < 192; i += 64) cwL[i] = ldf(chebv, i, isf32);
    for (int i = tid; i < 216; i += 64) {
        w1L[i] = ldf(g1wv, (size_t)i * 3 + 1, isf32);
        w2L[i] = ldf(g2wv, (size_t)i * 3 + 1, isf32);
    }
    if (tid < 12) {
        wbL[tid]      = ldf(gcnbv, tid, isf32);
        wbL[12 + tid] = ldf(g1bv, tid, isf32);
        wbL[24 + tid] = ldf(g2bv, tid, isf32);
    }
    __syncthreads();

    const int g = blockIdx.x * 64 + tid;
    const int b = g >> 12;
    const int n = g & (NNODES - 1);

    float y[3][12];
#pragma unroll
    for (int k = 0; k < 3; k++)
#pragma unroll
        for (int t = 0; t < 12; t++) y[k][t] = 0.f;

    for (int m0 = 0; m0 < NNODES; m0 += 8) {
        float a0[8], a1[8], a2[8];
        ld8(a0, adjv, ((size_t)(0 * NNODES + n)) * NNODES + m0, isf32);
        ld8(a1, adjv, ((size_t)(1 * NNODES + n)) * NNODES + m0, isf32);
        ld8(a2, adjv, ((size_t)(2 * NNODES + n)) * NNODES + m0, isf32);
#pragma unroll
        for (int t = 0; t < 12; t++) {
            float x8[8];
            ld8(x8, xv, ((size_t)(b * 12 + t)) * NNODES + m0, isf32);
#pragma unroll
            for (int j = 0; j < 8; j++) {
                y[0][t] += a0[j] * x8[j];
                y[1][t] += a1[j] * x8[j];
                y[2][t] += a2[j] * x8[j];
            }
        }
    }

    float sg[12];
#pragma unroll
    for (int o = 0; o < 12; o++) sg[o] = wbL[o];
    for (int t = 0; t < 12; t++) {
        const float y0 = y[0][t], y1 = y[1][t], y2 = y[2][t];
        const float* gwt = gwL + t * 768;
#pragma unroll 4
        for (int j = 0; j < 64; j++) {
            float h = y0 * cwL[j * 3] + y1 * cwL[j * 3 + 1] + y2 * cwL[j * 3 + 2];
            h = fmaxf(h, 0.f);
#pragma unroll
            for (int o = 0; o < 12; o++) sg[o] += h * gwt[j * 12 + o];
        }
    }

    float xa[18], xg[18];
#pragma unroll
    for (int c = 0; c < 6; c++)
#pragma unroll
        for (int kh = 0; kh < 3; kh++) {
            int m = n + 2 * kh - 2;
            bool ok = ((unsigned)m < (unsigned)NNODES);
            xa[c * 3 + kh] = ok ? ldf(xv, ((size_t)(b * 12 + c)) * NNODES + m, isf32) : 0.f;
            xg[c * 3 + kh] = ok ? ldf(xv, ((size_t)(b * 12 + c + 6)) * NNODES + m, isf32) : 0.f;
        }

#pragma unroll
    for (int o = 0; o < 12; o++) {
        float av = wbL[12 + o], gv = wbL[24 + o];
#pragma unroll
        for (int i = 0; i < 18; i++) {
            av += xa[i] * w1L[o * 18 + i];
            gv += xg[i] * w2L[o * 18 + i];
        }
        float s = 1.f / (1.f + expf(-gv));
        out[((size_t)(b * 12 + o)) * NNODES + n] = av * s + sg[o];
    }
}

// ---------------------------------------------------------------------------
extern "C" void kernel_launch(void* const* d_in, const int* in_sizes, int n_in,
                              void* d_out, int out_size, void* d_ws, size_t ws_size,
                              hipStream_t stream)
{
    int* flag = (int*)d_ws;                               // 64 B reserved
    __hip_bfloat16* xbf = (__hip_bfloat16*)((char*)d_ws + 64);      // 768 KB
    float* yws = (float*)((char*)d_ws + 64 + (size_t)NCOLS * NNODES * 2);
    const size_t need = 64 + (size_t)NCOLS * NNODES * 2
                      + (size_t)KSEG * NROWS * NCOLS * 4;

    hipLaunchKernelGGL(probe_dtype, dim3(1), dim3(64), 0, stream,
                       (const unsigned int*)d_in[1], flag);

    if (ws_size >= need) {
        hipLaunchKernelGGL(cvt_x, dim3(192), dim3(256), 0, stream,
                           d_in[0], xbf, flag);
        hipLaunchKernelGGL(gemm_y, dim3(256 * KSEG), dim3(192), 0, stream,
                           d_in[1], xbf, yws, flag);
        hipLaunchKernelGGL(epilogue_kernel, dim3(512), dim3(256), 0, stream,
                           d_in[0], yws, d_in[2], d_in[3], d_in[4],
                           d_in[5], d_in[6], d_in[7], d_in[8],
                           (float*)d_out, flag);
    } else {
        hipLaunchKernelGGL(fused_simple, dim3(512), dim3(64), 0, stream,
                           d_in[0], d_in[1], d_in[2], d_in[3], d_in[4],
                           d_in[5], d_in[6], d_in[7], d_in[8],
                           (float*)d_out, flag);
    }
}

// Round 4
// 375.910 us; speedup vs baseline: 1.1683x; 1.1233x over previous
//
#include <hip/hip_runtime.h>
#include <hip/hip_bf16.h>
#include <math.h>

#define NNODES 4096
#define NCOLS  96          // B*T
#define NROWS  12288       // K*NNODES
#define KSEG   16          // K-split ways
#define KLEN   (NNODES / KSEG)   // 256
#define NST    (KLEN / 32)       // 8 MFMA k-steps per wave

typedef __attribute__((ext_vector_type(8))) short short8;
typedef __attribute__((ext_vector_type(4))) float float4v;

// ---------------------------------------------------------------------------
// Dtype probe: flag[0]=1 => inputs fp32, 0 => bf16. (Validated: fp32 on this
// harness.)
// ---------------------------------------------------------------------------
__global__ void probe_dtype(const unsigned int* __restrict__ aw, int* __restrict__ flag) {
    int tid = threadIdx.x;
    unsigned w = aw[tid];
    unsigned e = (w >> 7) & 0xffu;
    bool insane = (e >= 0xC0u) || (e <= 0x30u);
    unsigned long long m = __ballot(insane);
    if (tid == 0) flag[0] = (__popcll(m) >= 16) ? 1 : 0;
}

__device__ __forceinline__ float ldf(const void* p, size_t i, int isf32) {
    return isf32 ? ((const float*)p)[i]
                 : __bfloat162float(((const __hip_bfloat16*)p)[i]);
}

__device__ __forceinline__ void ld8(float* d, const void* p, size_t e, int isf32) {
    if (isf32) {
        const float4* s = (const float4*)((const float*)p + e);
        float4 f0 = s[0], f1 = s[1];
        d[0] = f0.x; d[1] = f0.y; d[2] = f0.z; d[3] = f0.w;
        d[4] = f1.x; d[5] = f1.y; d[6] = f1.z; d[7] = f1.w;
    } else {
        const __hip_bfloat16* s = (const __hip_bfloat16*)p + e;
#pragma unroll
        for (int j = 0; j < 8; j++) d[j] = __bfloat162float(s[j]);
    }
}

// pack 8 fp32 -> short8 of bf16 (RNE via __float2bfloat16)
__device__ __forceinline__ short8 cvt8(float4 a, float4 b) {
    union { short8 v; __hip_bfloat16 h[8]; } u;
    u.h[0] = __float2bfloat16(a.x); u.h[1] = __float2bfloat16(a.y);
    u.h[2] = __float2bfloat16(a.z); u.h[3] = __float2bfloat16(a.w);
    u.h[4] = __float2bfloat16(b.x); u.h[5] = __float2bfloat16(b.y);
    u.h[6] = __float2bfloat16(b.z); u.h[7] = __float2bfloat16(b.w);
    return u.v;
}

// ---------------------------------------------------------------------------
// Kernel 0b: convert X (96 x 4096) to bf16 in workspace (once; L2/L3-resident
// thereafter). 192 blocks x 256 thr x 8 elems.
// ---------------------------------------------------------------------------
__global__ __launch_bounds__(256) void cvt_x(
    const void* __restrict__ xv, __hip_bfloat16* __restrict__ xbf,
    const int* __restrict__ flag)
{
    const int isf32 = flag[0];
    const int i = (blockIdx.x * 256 + threadIdx.x) * 8;
    if (isf32) {
        const float* xf = (const float*)xv;
        float4 f0 = *(const float4*)(xf + i);
        float4 f1 = *(const float4*)(xf + i + 4);
        short8 v = cvt8(f0, f1);
        *(short8*)(xbf + i) = v;
    } else {
        *(uint4*)(xbf + i) = *(const uint4*)((const __hip_bfloat16*)xv + i);
    }
}

// ---------------------------------------------------------------------------
// Kernel 1 (v4): y = adj @ X^T, bf16 MFMA 16x16x32. BARRIER-FREE K-loop.
// KSEG=16: per-block X slice = 96 rows x 256 k bf16 = 48 KB -> fits LDS
// whole. Stage once (single __syncthreads), then the K-loop has NO sync at
// all: adj streams global->reg (2-deep, fully static), X fragments come from
// read-only swizzled LDS (chunk' = c ^ (row&7), conflict-free ds_read_b128).
// No barriers => no vmcnt drains => compiler schedules loads deep; TLP from
// 512-thr blocks, 48 KB LDS, launch_bounds(512,4) -> 2-3 blocks/CU.
// Grid 96 rowgroups x 16 ksegs = 1536 blocks; wave owns 16 rows x 256 k.
// Output: yws slice ks; C/D mapping P0: col=lane&15, row=(lane>>4)*4+reg.
// ---------------------------------------------------------------------------
__global__ __launch_bounds__(512, 4) void gemm_y(
    const void* __restrict__ adjv, const __hip_bfloat16* __restrict__ xbf,
    float* __restrict__ yws, const int* __restrict__ flag)
{
    __shared__ uint4 Xs[96 * 32];   // 48 KB, swizzled 16B chunks

    const int tid = threadIdx.x;
    const int isf32 = flag[0];
    const int wv = tid >> 6, ln = tid & 63, fr = ln & 15, fq = ln >> 4;

    const int bid = blockIdx.x;
    const int rt0 = (bid >> 4) * 128;   // 128 rows per block (8 waves x 16)
    const int ks  = bid & 15;
    const int k0  = ks * KLEN;

    // ---- stage X slice: 96*32 = 3072 chunks of 16B, 6 per thread ----
#pragma unroll
    for (int s = 0; s < 6; s++) {
        int L = tid + s * 512;
        int r = L >> 5, c = L & 31;
        Xs[r * 32 + (c ^ (r & 7))] =
            *(const uint4*)(xbf + (size_t)r * NNODES + k0 + c * 8);
    }

    float4v acc[6];
#pragma unroll
    for (int i = 0; i < 6; i++) acc[i] = (float4v){0.f, 0.f, 0.f, 0.f};

    const int arow = rt0 + wv * 16 + fr;   // this lane's adj row
    __syncthreads();                       // the ONLY barrier

#define XFRAG(CT, STEP) \
    (*(const short8*)&Xs[((CT) * 16 + fr) * 32 + ((((STEP) * 4) + fq) ^ (((CT) * 16 + fr) & 7))])

    if (isf32) {
        const float* ap = (const float*)adjv + (size_t)arow * NNODES + k0 + fq * 8;
        float4 AA[2], AB[2];

#define ALOADF(R, STEP) { const float* p = ap + (STEP) * 32;                   \
        R[0] = *(const float4*)p; R[1] = *(const float4*)(p + 4); }
#define COMPF(R, STEP) { short8 a = cvt8(R[0], R[1]);                          \
        _Pragma("unroll")                                                      \
        for (int ct = 0; ct < 6; ct++)                                         \
            acc[ct] = __builtin_amdgcn_mfma_f32_16x16x32_bf16(a, XFRAG(ct, STEP), acc[ct], 0, 0, 0); }

        ALOADF(AA, 0); ALOADF(AB, 1);
        COMPF(AA, 0);  ALOADF(AA, 2);
        COMPF(AB, 1);  ALOADF(AB, 3);
        COMPF(AA, 2);  ALOADF(AA, 4);
        COMPF(AB, 3);  ALOADF(AB, 5);
        COMPF(AA, 4);  ALOADF(AA, 6);
        COMPF(AB, 5);  ALOADF(AB, 7);
        COMPF(AA, 6);
        COMPF(AB, 7);
#undef ALOADF
#undef COMPF
    } else {
        // bf16 adj path (insurance): one uint4 per 32-k fragment
        const __hip_bfloat16* ap = (const __hip_bfloat16*)adjv + (size_t)arow * NNODES + k0 + fq * 8;
        uint4 AA, AB;

#define ALOADB(R, STEP) R = *(const uint4*)(ap + (STEP) * 32);
#define COMPB(R, STEP) { short8 a = *(const short8*)&R;                        \
        _Pragma("unroll")                                                      \
        for (int ct = 0; ct < 6; ct++)                                         \
            acc[ct] = __builtin_amdgcn_mfma_f32_16x16x32_bf16(a, XFRAG(ct, STEP), acc[ct], 0, 0, 0); }

        ALOADB(AA, 0); ALOADB(AB, 1);
        COMPB(AA, 0);  ALOADB(AA, 2);
        COMPB(AB, 1);  ALOADB(AB, 3);
        COMPB(AA, 2);  ALOADB(AA, 4);
        COMPB(AB, 3);  ALOADB(AB, 5);
        COMPB(AA, 4);  ALOADB(AA, 6);
        COMPB(AB, 5);  ALOADB(AB, 7);
        COMPB(AA, 6);
        COMPB(AB, 7);
#undef ALOADB
#undef COMPB
    }
#undef XFRAG

    // store partials: slice ks, P0 mapping
    float* yo = yws + (size_t)ks * NROWS * NCOLS;
#pragma unroll
    for (int ct = 0; ct < 6; ct++)
#pragma unroll
        for (int rg = 0; rg < 4; rg++) {
            size_t r = (size_t)rt0 + wv * 16 + fq * 4 + rg;
            yo[r * NCOLS + ct * 16 + fr] = acc[ct][rg];
        }
}

// ---------------------------------------------------------------------------
// Kernel 2: epilogue. 4 lanes (a quad) per (b,n): each lane owns 3 t's of the
// cheb/sgc sum, quad-reduced via shfl_xor; GLU o-range split across the quad.
// Sums the KSEG=16 partial slices of yws. 512 blocks x 256 thr.
// yws slice layout [k*4096+n][b*12+t].
// ---------------------------------------------------------------------------
__global__ __launch_bounds__(256) void epilogue_kernel(
    const void* __restrict__ xv, const float* __restrict__ yws,
    const void* __restrict__ chebv, const void* __restrict__ gcnwv,
    const void* __restrict__ gcnbv, const void* __restrict__ g1wv,
    const void* __restrict__ g1bv, const void* __restrict__ g2wv,
    const void* __restrict__ g2bv,
    float* __restrict__ out, const int* __restrict__ flag)
{
    __shared__ float gwL[9216];   // [t][j*12+o]
    __shared__ float cwL[192];    // [j*3+k]
    __shared__ float w1L[216];    // [o*18 + c*3 + kh]  (kw=1 tap)
    __shared__ float w2L[216];
    __shared__ float wbL[36];

    const int tid = threadIdx.x;
    const int isf32 = flag[0];

    for (int i = tid; i < 9216; i += 256) {
        int o = i / 768, t = (i / 64) % 12, j = i % 64;   // gcn_w flat (o,t,0,j)
        gwL[t * 768 + j * 12 + o] = ldf(gcnwv, i, isf32);
    }
    if (tid < 192) cwL[tid] = ldf(chebv, tid, isf32);
    if (tid < 216) {
        w1L[tid] = ldf(g1wv, (size_t)tid * 3 + 1, isf32);
        w2L[tid] = ldf(g2wv, (size_t)tid * 3 + 1, isf32);
    }
    if (tid < 12) {
        wbL[tid]      = ldf(gcnbv, tid, isf32);
        wbL[12 + tid] = ldf(g1bv, tid, isf32);
        wbL[24 + tid] = ldf(g2bv, tid, isf32);
    }
    __syncthreads();

    const int gid = blockIdx.x * 256 + tid;   // 0..131071
    const int pr  = gid >> 2;                 // (b,n) pair 0..32767
    const int tq  = gid & 3;                  // t-quarter 0..3
    const int b = pr >> 12;
    const int n = pr & (NNODES - 1);

    // y values for this lane's 3 t's: sum the KSEG partial slices
    float yk[3][3];
#pragma unroll
    for (int k = 0; k < 3; k++) { yk[k][0] = 0.f; yk[k][1] = 0.f; yk[k][2] = 0.f; }
#pragma unroll 4
    for (int s = 0; s < KSEG; s++) {
        const float* base = yws + (size_t)s * NROWS * NCOLS;
#pragma unroll
        for (int k = 0; k < 3; k++) {
            const float* yp = base + ((size_t)(k * NNODES + n)) * NCOLS + b * 12 + tq * 3;
            yk[k][0] += yp[0]; yk[k][1] += yp[1]; yk[k][2] += yp[2];
        }
    }

    // ---- cheb -> relu -> partial sgc over 3 t's ----
    float sg[12];
#pragma unroll
    for (int o = 0; o < 12; o++) sg[o] = 0.f;
#pragma unroll
    for (int i = 0; i < 3; i++) {
        const float y0 = yk[0][i], y1 = yk[1][i], y2 = yk[2][i];
        const float* gwt = gwL + (tq * 3 + i) * 768;
#pragma unroll 4
        for (int j = 0; j < 64; j++) {
            float h = y0 * cwL[j * 3] + y1 * cwL[j * 3 + 1] + y2 * cwL[j * 3 + 2];
            h = fmaxf(h, 0.f);
#pragma unroll
            for (int o = 0; o < 12; o++) sg[o] += h * gwt[j * 12 + o];
        }
    }
    // quad reduction: all 4 lanes end with the full t-sum
#pragma unroll
    for (int o = 0; o < 12; o++) {
        sg[o] += __shfl_xor(sg[o], 1);
        sg[o] += __shfl_xor(sg[o], 2);
    }

    // ---- GLU (dilated conv taps n-2, n, n+2; only kw=1 alive); this lane
    // handles o = tq*3 .. tq*3+2 ----
    float xa[18], xg[18];
#pragma unroll
    for (int c = 0; c < 6; c++)
#pragma unroll
        for (int kh = 0; kh < 3; kh++) {
            int m = n + 2 * kh - 2;
            bool ok = ((unsigned)m < (unsigned)NNODES);
            xa[c * 3 + kh] = ok ? ldf(xv, ((size_t)(b * 12 + c)) * NNODES + m, isf32) : 0.f;
            xg[c * 3 + kh] = ok ? ldf(xv, ((size_t)(b * 12 + c + 6)) * NNODES + m, isf32) : 0.f;
        }

#pragma unroll
    for (int i = 0; i < 3; i++) {
        const int o = tq * 3 + i;
        float av = wbL[12 + o], gv = wbL[24 + o];
#pragma unroll
        for (int q = 0; q < 18; q++) {
            av += xa[q] * w1L[o * 18 + q];
            gv += xg[q] * w2L[o * 18 + q];
        }
        float s = 1.f / (1.f + expf(-gv));
        out[((size_t)(b * 12 + o)) * NNODES + n] = av * s + sg[o] + wbL[o];
    }
}

// ---------------------------------------------------------------------------
// Fallback single kernel (only if ws too small): round-5 verified path.
// ---------------------------------------------------------------------------
__global__ __launch_bounds__(64) void fused_simple(
    const void* __restrict__ xv, const void* __restrict__ adjv,
    const void* __restrict__ chebv, const void* __restrict__ gcnwv,
    const void* __restrict__ gcnbv, const void* __restrict__ g1wv,
    const void* __restrict__ g1bv, const void* __restrict__ g2wv,
    const void* __restrict__ g2bv,
    float* __restrict__ out, const int* __restrict__ flag)
{
    __shared__ float gwL[9216];
    __shared__ float cwL[192];
    __shared__ float w1L[216];
    __shared__ float w2L[216];
    __shared__ float wbL[36];

    const int tid = threadIdx.x;
    const int isf32 = flag[0];

    for (int i = tid; i < 9216; i += 64) {
        int o = i / 768, t = (i / 64) % 12, j = i % 64;
        gwL[t * 768 + j * 12 + o] = ldf(gcnwv, i, isf32);
    }
    for (int i = tid; i < 192; i += 64) cwL[i] = ldf(chebv, i, isf32);
    for (int i = tid; i < 216; i += 64) {
        w1L[i] = ldf(g1wv, (size_t)i * 3 + 1, isf32);
        w2L[i] = ldf(g2wv, (size_t)i * 3 + 1, isf32);
    }
    if (tid < 12) {
        wbL[tid]      = ldf(gcnbv, tid, isf32);
        wbL[12 + tid] = ldf(g1bv, tid, isf32);
        wbL[24 + tid] = ldf(g2bv, tid, isf32);
    }
    __syncthreads();

    const int g = blockIdx.x * 64 + tid;
    const int b = g >> 12;
    const int n = g & (NNODES - 1);

    float y[3][12];
#pragma unroll
    for (int k = 0; k < 3; k++)
#pragma unroll
        for (int t = 0; t < 12; t++) y[k][t] = 0.f;

    for (int m0 = 0; m0 < NNODES; m0 += 8) {
        float a0[8], a1[8], a2[8];
        ld8(a0, adjv, ((size_t)(0 * NNODES + n)) * NNODES + m0, isf32);
        ld8(a1, adjv, ((size_t)(1 * NNODES + n)) * NNODES + m0, isf32);
        ld8(a2, adjv, ((size_t)(2 * NNODES + n)) * NNODES + m0, isf32);
#pragma unroll
        for (int t = 0; t < 12; t++) {
            float x8[8];
            ld8(x8, xv, ((size_t)(b * 12 + t)) * NNODES + m0, isf32);
#pragma unroll
            for (int j = 0; j < 8; j++) {
                y[0][t] += a0[j] * x8[j];
                y[1][t] += a1[j] * x8[j];
                y[2][t] += a2[j] * x8[j];
            }
        }
    }

    float sg[12];
#pragma unroll
    for (int o = 0; o < 12; o++) sg[o] = wbL[o];
    for (int t = 0; t < 12; t++) {
        const float y0 = y[0][t], y1 = y[1][t], y2 = y[2][t];
        const float* gwt = gwL + t * 768;
#pragma unroll 4
        for (int j = 0; j < 64; j++) {
            float h = y0 * cwL[j * 3] + y1 * cwL[j * 3 + 1] + y2 * cwL[j * 3 + 2];
            h = fmaxf(h, 0.f);
#pragma unroll
            for (int o = 0; o < 12; o++) sg[o] += h * gwt[j * 12 + o];
        }
    }

    float xa[18], xg[18];
#pragma unroll
    for (int c = 0; c < 6; c++)
#pragma unroll
        for (int kh = 0; kh < 3; kh++) {
            int m = n + 2 * kh - 2;
            bool ok = ((unsigned)m < (unsigned)NNODES);
            xa[c * 3 + kh] = ok ? ldf(xv, ((size_t)(b * 12 + c)) * NNODES + m, isf32) : 0.f;
            xg[c * 3 + kh] = ok ? ldf(xv, ((size_t)(b * 12 + c + 6)) * NNODES + m, isf32) : 0.f;
        }

#pragma unroll
    for (int o = 0; o < 12; o++) {
        float av = wbL[12 + o], gv = wbL[24 + o];
#pragma unroll
        for (int i = 0; i < 18; i++) {
            av += xa[i] * w1L[o * 18 + i];
            gv += xg[i] * w2L[o * 18 + i];
        }
        float s = 1.f / (1.f + expf(-gv));
        out[((size_t)(b * 12 + o)) * NNODES + n] = av * s + sg[o];
    }
}

// ---------------------------------------------------------------------------
extern "C" void kernel_launch(void* const* d_in, const int* in_sizes, int n_in,
                              void* d_out, int out_size, void* d_ws, size_t ws_size,
                              hipStream_t stream)
{
    int* flag = (int*)d_ws;                               // 64 B reserved
    __hip_bfloat16* xbf = (__hip_bfloat16*)((char*)d_ws + 64);      // 768 KB
    float* yws = (float*)((char*)d_ws + 64 + (size_t)NCOLS * NNODES * 2);
    const size_t need = 64 + (size_t)NCOLS * NNODES * 2
                      + (size_t)KSEG * NROWS * NCOLS * 4;

    hipLaunchKernelGGL(probe_dtype, dim3(1), dim3(64), 0, stream,
                       (const unsigned int*)d_in[1], flag);

    if (ws_size >= need) {
        hipLaunchKernelGGL(cvt_x, dim3(192), dim3(256), 0, stream,
                           d_in[0], xbf, flag);
        hipLaunchKernelGGL(gemm_y, dim3(96 * KSEG), dim3(512), 0, stream,
                           d_in[1], xbf, yws, flag);
        hipLaunchKernelGGL(epilogue_kernel, dim3(512), dim3(256), 0, stream,
                           d_in[0], yws, d_in[2], d_in[3], d_in[4],
                           d_in[5], d_in[6], d_in[7], d_in[8],
                           (float*)d_out, flag);
    } else {
        hipLaunchKernelGGL(fused_simple, dim3(512), dim3(64), 0, stream,
                           d_in[0], d_in[1], d_in[2], d_in[3], d_in[4],
                           d_in[5], d_in[6], d_in[7], d_in[8],
                           (float*)d_out, flag);
    }
}